// Round 1
// baseline (285.974 us; speedup 1.0000x reference)
//
#include <hip/hip_runtime.h>

#define T_LEN 2048
#define S_LEN 512
#define D_LEN 128
#define BT 64
#define BG 80
#define THREADS 1024

// out[t][s] = (1 - ||z_t - G[t+511-s]||^2 / 128)^3
//   G[g] = init[511-g] (g<512), else x[g-512]
// Norm trick: ||z-w||^2 = ||z||^2 + ||w||^2 - 2 z.w  -> inner loop is pure FMA.
//
// v2: occupancy fix. 256 blocks (8 g-tiles x 32 t-tiles of 64x80) = exactly
// 1 block/CU, 1024 threads = 16 waves/CU = 4 waves/SIMD (was 1.1).
// K split 4-ways across thread slices (tid>>8); partials combined via LDS
// (reusing the zt/gt region after a barrier). Per-thread 4x5 register tile
// keeps the LDS:VALU ratio (9 ds_read_b128 : 100 v_fmac per k-step) VALU-bound.
// k-loop fully unrolled with XOR-commuted iteration order so g-side reads get
// compile-time immediate offsets (sum over k is order-invariant).

__global__ __launch_bounds__(THREADS, 4)
void mmd_kernel(const float* __restrict__ x, const float* __restrict__ init,
                float* __restrict__ out) {
    __shared__ float lds[(BT + BG) * D_LEN];   // 73,728 B; zt then gt
    __shared__ float znorm[BT];
    __shared__ float gnorm[BG];

    float* zt = lds;
    float* gt = lds + BT * D_LEN;

    const int bt = blockIdx.y;      // t-tile: 0..31
    const int j  = blockIdx.x;      // g-tile within band: 0..7
    const int t0 = bt * BT;
    const int g0 = t0 + j * BG;

    const int tid = threadIdx.x;

    // ---- stage z tile (64 rows x 32 float4), XOR swizzle on float4 columns
    {
        int idx = tid;
        #pragma unroll
        for (int k = 0; k < 2; ++k, idx += THREADS) {
            const int row = idx >> 5;
            const int c4  = idx & 31;
            const float4 v = *(const float4*)(x + (t0 + row) * D_LEN + c4 * 4);
            *(float4*)(zt + row * D_LEN + ((c4 ^ (row & 7)) << 2)) = v;
        }
    }
    // ---- stage G tile (80 rows x 32 float4); clamp g (tail tiles read past
    //      the band; clamped rows only feed masked-out outputs)
    for (int idx = tid; idx < BG * 32; idx += THREADS) {
        const int row = idx >> 5;
        const int c4  = idx & 31;
        int g = g0 + row;
        if (g > T_LEN + S_LEN - 1) g = T_LEN + S_LEN - 1;
        const float* src = (g >= S_LEN) ? (x + (g - S_LEN) * D_LEN)
                                        : (init + (S_LEN - 1 - g) * D_LEN);
        const float4 v = *(const float4*)(src + c4 * 4);
        *(float4*)(gt + row * D_LEN + ((c4 ^ (row & 7)) << 2)) = v;
    }
    __syncthreads();

    // ---- row norms: 144 rows x 4 threads/row (waves 0..8), 4-lane shuffle
    if (tid < (BT + BG) * 4) {
        const int row = tid >> 2;           // 0..143
        const int q   = tid & 3;
        const float* base = (row < BT) ? (zt + row * D_LEN)
                                       : (gt + (row - BT) * D_LEN);
        const int r7 = row & 7;             // == (row-64)&7 for g rows (64%8==0)
        float s = 0.f;
        #pragma unroll
        for (int c = 0; c < 8; ++c) {
            const int c4 = q * 8 + c;
            const float4 v = *(const float4*)(base + ((c4 ^ r7) << 2));
            s += v.x * v.x + v.y * v.y + v.z * v.z + v.w * v.w;
        }
        s += __shfl_xor(s, 1);
        s += __shfl_xor(s, 2);
        if (q == 0) {
            if (row < BT) znorm[row] = s;
            else          gnorm[row - BT] = s;
        }
    }

    const int sl = tid >> 8;       // k-slice 0..3  (wave-uniform)
    const int id = tid & 255;
    const int tx = id & 15;        // g-dir
    const int ty = id >> 4;        // t-dir

    float dot[4][5];
    #pragma unroll
    for (int i = 0; i < 4; ++i)
        #pragma unroll
        for (int jj = 0; jj < 5; ++jj) dot[i][jj] = 0.f;

    // Per-thread swizzle keys. k4 = sl*8 + kk; columns read at (k4 ^ key)<<2.
    // Iterate m = kk ^ gsw: g-side column becomes sl*32 + (m<<2)  (immediate),
    // z-side column becomes sl*32 + ((m<<2) ^ e4), e4 = ((ty^tx)&7)<<2.
    const int e4 = ((ty ^ tx) & 7) << 2;
    int zb[4], wbase[5];
    #pragma unroll
    for (int i = 0; i < 4; ++i)  zb[i]    = (i * 16 + ty) * D_LEN + sl * 32;
    #pragma unroll
    for (int jj = 0; jj < 5; ++jj) wbase[jj] = (jj * 16 + tx) * D_LEN + sl * 32;

    #pragma unroll
    for (int m = 0; m < 8; ++m) {
        const int zc = (m << 2) ^ e4;
        float4 za[4], w[5];
        #pragma unroll
        for (int i = 0; i < 4; ++i)
            za[i] = *(const float4*)(zt + zb[i] + zc);
        #pragma unroll
        for (int jj = 0; jj < 5; ++jj)
            w[jj] = *(const float4*)(gt + wbase[jj] + (m << 2));
        #pragma unroll
        for (int i = 0; i < 4; ++i)
            #pragma unroll
            for (int jj = 0; jj < 5; ++jj)
                dot[i][jj] += za[i].x * w[jj].x + za[i].y * w[jj].y
                            + za[i].z * w[jj].z + za[i].w * w[jj].w;
    }
    __syncthreads();   // all LDS reads of zt/gt done -> region reusable

    // ---- write partials for row-groups we don't finalize (stride-1, no conflicts)
    #pragma unroll
    for (int i = 0; i < 4; ++i) {
        if (i == sl) continue;
        const int src = (sl < i) ? sl : sl - 1;
        #pragma unroll
        for (int jj = 0; jj < 5; ++jj)
            lds[((i * 3 + src) * 5 + jj) * 256 + id] = dot[i][jj];
    }
    __syncthreads();

    // ---- combine + epilogue: slice sl finalizes row-group i = sl
    const int tr = sl * 16 + ty;
    const int t  = t0 + tr;
    const float zn = znorm[tr];
    #pragma unroll
    for (int jj = 0; jj < 5; ++jj) {
        float tot = dot[sl][jj];
        #pragma unroll
        for (int src = 0; src < 3; ++src)
            tot += lds[((sl * 3 + src) * 5 + jj) * 256 + id];
        const int gr = jj * 16 + tx;
        const int g  = g0 + gr;
        const int so = t + (S_LEN - 1) - g;
        if (so >= 0 && so < S_LEN) {
            const float dist = zn + gnorm[gr] - 2.f * tot;
            const float p = 1.f - dist * (1.f / (float)D_LEN);
            out[t * S_LEN + so] = p * p * p;
        }
    }
}

extern "C" void kernel_launch(void* const* d_in, const int* in_sizes, int n_in,
                              void* d_out, int out_size, void* d_ws, size_t ws_size,
                              hipStream_t stream) {
    (void)in_sizes; (void)n_in; (void)out_size; (void)d_ws; (void)ws_size;
    const float* x    = (const float*)d_in[0];   // (1,2048,1,128) -> (2048,128)
    const float* init = (const float*)d_in[1];   // (512,128)
    float* out = (float*)d_out;                  // (1,2048,512) fp32

    dim3 grid(8, 32);   // 256 blocks: exactly 1 per CU
    mmd_kernel<<<grid, THREADS, 0, stream>>>(x, init, out);
}

// Round 2
// 106.931 us; speedup vs baseline: 2.6744x; 2.6744x over previous
//
#include <hip/hip_runtime.h>

#define T_LEN 2048
#define S_LEN 512
#define D_LEN 128
#define BT 64
#define BG 80
#define THREADS 1024

// out[t][s] = (1 - ||z_t - G[t+511-s]||^2 / 128)^3
//   G[g] = init[511-g] (g<512), else x[g-512]
// Norm trick: ||z-w||^2 = ||z||^2 + ||w||^2 - 2 z.w  -> inner loop is pure FMA.
//
// v3 = v2 occupancy structure with the two v2 bugs fixed:
//  - NO runtime-indexed register arrays (v2's dot[sl][jj] -> scratch, 500MB
//    spill traffic). Rotation trick: slice sl computes row-groups
//    (sl+i)&3 into dot[i]; "my" group is always dot[0] (static index).
//  - Both LDS read sides use the row-XOR swizzle (v2 read gt un-swizzled ->
//    16-way bank conflict, 1e7 events). z-side is broadcast, g-side 2-way: free.
// 256 blocks (8 x 32) = 1 block/CU, 1024 thr = 4 waves/SIMD.
// K split 4 ways over slices sl = tid>>8; partials combined via LDS (region
// reused behind a barrier). Per-thread 4x5 register tile.

__global__ __launch_bounds__(THREADS, 4)
void mmd_kernel(const float* __restrict__ x, const float* __restrict__ init,
                float* __restrict__ out) {
    __shared__ float lds[(BT + BG) * D_LEN];   // 73,728 B; zt then gt
    __shared__ float znorm[BT];
    __shared__ float gnorm[BG];

    float* zt = lds;
    float* gt = lds + BT * D_LEN;

    const int bt = blockIdx.y;      // t-tile: 0..31
    const int j  = blockIdx.x;      // g-tile within band: 0..7
    const int t0 = bt * BT;
    const int g0 = t0 + j * BG;

    const int tid = threadIdx.x;

    // ---- stage z tile (64 rows x 32 float4), XOR swizzle on float4 columns
    {
        int idx = tid;
        #pragma unroll
        for (int k = 0; k < 2; ++k, idx += THREADS) {
            const int row = idx >> 5;
            const int c4  = idx & 31;
            const float4 v = *(const float4*)(x + (t0 + row) * D_LEN + c4 * 4);
            *(float4*)(zt + row * D_LEN + ((c4 ^ (row & 7)) << 2)) = v;
        }
    }
    // ---- stage G tile (80 rows x 32 float4); clamp g (tail tiles read past
    //      the band; clamped rows only feed masked-out outputs)
    for (int idx = tid; idx < BG * 32; idx += THREADS) {
        const int row = idx >> 5;
        const int c4  = idx & 31;
        int g = g0 + row;
        if (g > T_LEN + S_LEN - 1) g = T_LEN + S_LEN - 1;
        const float* src = (g >= S_LEN) ? (x + (g - S_LEN) * D_LEN)
                                        : (init + (S_LEN - 1 - g) * D_LEN);
        const float4 v = *(const float4*)(src + c4 * 4);
        *(float4*)(gt + row * D_LEN + ((c4 ^ (row & 7)) << 2)) = v;
    }
    __syncthreads();

    // ---- row norms: 144 rows x 4 threads/row (waves 0..8), 4-lane shuffle
    if (tid < (BT + BG) * 4) {
        const int row = tid >> 2;           // 0..143
        const int q   = tid & 3;
        const float* base = (row < BT) ? (zt + row * D_LEN)
                                       : (gt + (row - BT) * D_LEN);
        const int r7 = row & 7;             // == (row-64)&7 for g rows (64%8==0)
        float s = 0.f;
        #pragma unroll
        for (int c = 0; c < 8; ++c) {
            const int c4 = q * 8 + c;
            const float4 v = *(const float4*)(base + ((c4 ^ r7) << 2));
            s += v.x * v.x + v.y * v.y + v.z * v.z + v.w * v.w;
        }
        s += __shfl_xor(s, 1);
        s += __shfl_xor(s, 2);
        if (q == 0) {
            if (row < BT) znorm[row] = s;
            else          gnorm[row - BT] = s;
        }
    }

    const int sl = tid >> 8;       // k-slice 0..3  (wave-uniform)
    const int id = tid & 255;
    const int tx = id & 15;        // g-dir
    const int ty = id >> 4;        // t-dir

    // dot[i][jj] accumulates row-group (sl+i)&3 -- ALL register indices static.
    float dot[4][5];
    #pragma unroll
    for (int i = 0; i < 4; ++i)
        #pragma unroll
        for (int jj = 0; jj < 5; ++jj) dot[i][jj] = 0.f;

    const int zsw = ty & 7;        // z row swizzle key (row&7 == ty&7)
    const int gsw = tx & 7;        // g row swizzle key
    int zb[4], wb[5];
    #pragma unroll
    for (int i = 0; i < 4; ++i)
        zb[i] = (((sl + i) & 3) * 16 + ty) * D_LEN + sl * 32;
    #pragma unroll
    for (int jj = 0; jj < 5; ++jj)
        wb[jj] = (jj * 16 + tx) * D_LEN + sl * 32;

    #pragma unroll
    for (int kk = 0; kk < 8; ++kk) {
        const int zc = (kk ^ zsw) << 2;
        const int gc = (kk ^ gsw) << 2;
        float4 za[4], w[5];
        #pragma unroll
        for (int i = 0; i < 4; ++i)
            za[i] = *(const float4*)(zt + zb[i] + zc);
        #pragma unroll
        for (int jj = 0; jj < 5; ++jj)
            w[jj] = *(const float4*)(gt + wb[jj] + gc);
        #pragma unroll
        for (int i = 0; i < 4; ++i)
            #pragma unroll
            for (int jj = 0; jj < 5; ++jj)
                dot[i][jj] += za[i].x * w[jj].x + za[i].y * w[jj].y
                            + za[i].z * w[jj].z + za[i].w * w[jj].w;
    }
    __syncthreads();   // all LDS reads of zt/gt done -> region reusable

    // ---- write partials for the 3 row-groups this slice doesn't finalize.
    // Group gi=(sl+i)&3 slot i-1; stride-1 in id -> conflict-free.
    #pragma unroll
    for (int i = 1; i < 4; ++i) {
        const int gi = (sl + i) & 3;
        #pragma unroll
        for (int jj = 0; jj < 5; ++jj)
            lds[((gi * 3 + (i - 1)) * 5 + jj) * 256 + id] = dot[i][jj];
    }
    __syncthreads();

    // ---- combine + epilogue: slice sl finalizes row-group sl (== dot[0])
    const int tr = sl * 16 + ty;
    const int t  = t0 + tr;
    const float zn = znorm[tr];
    #pragma unroll
    for (int jj = 0; jj < 5; ++jj) {
        float tot = dot[0][jj];
        #pragma unroll
        for (int src = 0; src < 3; ++src)
            tot += lds[((sl * 3 + src) * 5 + jj) * 256 + id];
        const int gr = jj * 16 + tx;
        const int g  = g0 + gr;
        const int so = t + (S_LEN - 1) - g;
        if (so >= 0 && so < S_LEN) {
            const float dist = zn + gnorm[gr] - 2.f * tot;
            const float p = 1.f - dist * (1.f / (float)D_LEN);
            out[t * S_LEN + so] = p * p * p;
        }
    }
}

extern "C" void kernel_launch(void* const* d_in, const int* in_sizes, int n_in,
                              void* d_out, int out_size, void* d_ws, size_t ws_size,
                              hipStream_t stream) {
    (void)in_sizes; (void)n_in; (void)out_size; (void)d_ws; (void)ws_size;
    const float* x    = (const float*)d_in[0];   // (1,2048,1,128) -> (2048,128)
    const float* init = (const float*)d_in[1];   // (512,128)
    float* out = (float*)d_out;                  // (1,2048,512) fp32

    dim3 grid(8, 32);   // 256 blocks: exactly 1 per CU
    mmd_kernel<<<grid, THREADS, 0, stream>>>(x, init, out);
}

// Round 3
// 106.898 us; speedup vs baseline: 2.6752x; 1.0003x over previous
//
#include <hip/hip_runtime.h>

#define T_LEN 2048
#define S_LEN 512
#define D_LEN 128
#define BT 64
#define BG 80
#define THREADS 1024

// out[t][s] = (1 - ||z_t - G[t+511-s]||^2 / 128)^3
//   G[g] = init[511-g] (g<512), else x[g-512]
// Norm trick: ||z-w||^2 = ||z||^2 + ||w||^2 - 2 z.w  -> inner loop is pure FMA.
//
// v4 = v3 with the VGPR-cap spill fixed and the norm phase folded into staging:
//  - v3's __launch_bounds__(1024,4) made the allocator target 2 blocks/CU
//    (32 waves) -> 64-VGPR budget -> ~100 floats/thread spilled to scratch
//    (113MB WRITE_SIZE, VALUBusy 12.5%). Fix: min-waves 1 + LDS padded past
//    80KB so exactly 1 block/CU fits -> 128-VGPR budget, no spill.
//  - Row norms now computed during staging via 32-lane __shfl_xor reduce
//    (each staging lane already holds its float4). Kills the separate norm
//    phase whose reads were 8-way bank-conflicted (729K conflict cycles).
// 256 blocks (8 x 32) = 1 block/CU, 1024 thr = 4 waves/SIMD.
// K split 4 ways over slices sl = tid>>8; partials combined via LDS (region
// reused behind a barrier). Per-thread 4x5 register tile; rotation trick
// keeps every register index compile-time static.

__global__ __launch_bounds__(THREADS, 1)
void mmd_kernel(const float* __restrict__ x, const float* __restrict__ init,
                float* __restrict__ out) {
    // 73,728 data floats + 2,048 pad floats = 82,944B static LDS:
    // 2 blocks would need >160KiB -> occupancy pinned to 1 block/CU,
    // so the register allocator budgets 128 VGPRs (16 waves) -> no spill.
    __shared__ float lds[(BT + BG) * D_LEN + 2048];
    __shared__ float znorm[BT];
    __shared__ float gnorm[BG];

    float* zt = lds;
    float* gt = lds + BT * D_LEN;

    const int bt = blockIdx.y;      // t-tile: 0..31
    const int j  = blockIdx.x;      // g-tile within band: 0..7
    const int t0 = bt * BT;
    const int g0 = t0 + j * BG;

    const int tid = threadIdx.x;

    // ---- stage z tile (64 rows x 32 float4), XOR swizzle on float4 columns.
    // Norm computed in-flight: 32 lanes per row (one row per wave-half),
    // __shfl_xor masks 1..16 reduce within the half.
    #pragma unroll
    for (int k = 0; k < 2; ++k) {
        const int idx = tid + k * THREADS;
        const int row = idx >> 5;
        const int c4  = idx & 31;
        const float4 v = *(const float4*)(x + (t0 + row) * D_LEN + c4 * 4);
        *(float4*)(zt + row * D_LEN + ((c4 ^ (row & 7)) << 2)) = v;
        float s = v.x * v.x + v.y * v.y + v.z * v.z + v.w * v.w;
        s += __shfl_xor(s, 1);
        s += __shfl_xor(s, 2);
        s += __shfl_xor(s, 4);
        s += __shfl_xor(s, 8);
        s += __shfl_xor(s, 16);
        if (c4 == 0) znorm[row] = s;
    }
    // ---- stage G tile (80 rows x 32 float4); clamp g (tail tiles read past
    //      the band; clamped rows only feed masked-out outputs).
    //      Third iteration: tid<512 -> waves 0..7 fully active (wave-uniform).
    #pragma unroll
    for (int k = 0; k < 3; ++k) {
        const int idx = tid + k * THREADS;
        if (idx < BG * 32) {
            const int row = idx >> 5;
            const int c4  = idx & 31;
            int g = g0 + row;
            if (g > T_LEN + S_LEN - 1) g = T_LEN + S_LEN - 1;
            const float* src = (g >= S_LEN) ? (x + (g - S_LEN) * D_LEN)
                                            : (init + (S_LEN - 1 - g) * D_LEN);
            const float4 v = *(const float4*)(src + c4 * 4);
            *(float4*)(gt + row * D_LEN + ((c4 ^ (row & 7)) << 2)) = v;
            float s = v.x * v.x + v.y * v.y + v.z * v.z + v.w * v.w;
            s += __shfl_xor(s, 1);
            s += __shfl_xor(s, 2);
            s += __shfl_xor(s, 4);
            s += __shfl_xor(s, 8);
            s += __shfl_xor(s, 16);
            if (c4 == 0) gnorm[row] = s;
        }
    }
    __syncthreads();

    const int sl = tid >> 8;       // k-slice 0..3  (wave-uniform)
    const int id = tid & 255;
    const int tx = id & 15;        // g-dir
    const int ty = id >> 4;        // t-dir

    // dot[i][jj] accumulates row-group (sl+i)&3 -- ALL register indices static.
    float dot[4][5];
    #pragma unroll
    for (int i = 0; i < 4; ++i)
        #pragma unroll
        for (int jj = 0; jj < 5; ++jj) dot[i][jj] = 0.f;

    const int zsw = ty & 7;        // z row swizzle key (row&7 == ty&7)
    const int gsw = tx & 7;        // g row swizzle key
    int zb[4], wb[5];
    #pragma unroll
    for (int i = 0; i < 4; ++i)
        zb[i] = (((sl + i) & 3) * 16 + ty) * D_LEN + sl * 32;
    #pragma unroll
    for (int jj = 0; jj < 5; ++jj)
        wb[jj] = (jj * 16 + tx) * D_LEN + sl * 32;

    #pragma unroll
    for (int kk = 0; kk < 8; ++kk) {
        const int zc = (kk ^ zsw) << 2;
        const int gc = (kk ^ gsw) << 2;
        float4 za[4], w[5];
        #pragma unroll
        for (int i = 0; i < 4; ++i)
            za[i] = *(const float4*)(zt + zb[i] + zc);
        #pragma unroll
        for (int jj = 0; jj < 5; ++jj)
            w[jj] = *(const float4*)(gt + wb[jj] + gc);
        #pragma unroll
        for (int i = 0; i < 4; ++i)
            #pragma unroll
            for (int jj = 0; jj < 5; ++jj)
                dot[i][jj] += za[i].x * w[jj].x + za[i].y * w[jj].y
                            + za[i].z * w[jj].z + za[i].w * w[jj].w;
    }
    __syncthreads();   // all LDS reads of zt/gt done -> region reusable

    // ---- write partials for the 3 row-groups this slice doesn't finalize.
    // Group gi=(sl+i)&3 slot i-1; stride-1 in id -> conflict-free.
    #pragma unroll
    for (int i = 1; i < 4; ++i) {
        const int gi = (sl + i) & 3;
        #pragma unroll
        for (int jj = 0; jj < 5; ++jj)
            lds[((gi * 3 + (i - 1)) * 5 + jj) * 256 + id] = dot[i][jj];
    }
    __syncthreads();

    // ---- combine + epilogue: slice sl finalizes row-group sl (== dot[0])
    const int tr = sl * 16 + ty;
    const int t  = t0 + tr;
    const float zn = znorm[tr];
    #pragma unroll
    for (int jj = 0; jj < 5; ++jj) {
        float tot = dot[0][jj];
        #pragma unroll
        for (int src = 0; src < 3; ++src)
            tot += lds[((sl * 3 + src) * 5 + jj) * 256 + id];
        const int gr = jj * 16 + tx;
        const int g  = g0 + gr;
        const int so = t + (S_LEN - 1) - g;
        if (so >= 0 && so < S_LEN) {
            const float dist = zn + gnorm[gr] - 2.f * tot;
            const float p = 1.f - dist * (1.f / (float)D_LEN);
            out[t * S_LEN + so] = p * p * p;
        }
    }
}

extern "C" void kernel_launch(void* const* d_in, const int* in_sizes, int n_in,
                              void* d_out, int out_size, void* d_ws, size_t ws_size,
                              hipStream_t stream) {
    (void)in_sizes; (void)n_in; (void)out_size; (void)d_ws; (void)ws_size;
    const float* x    = (const float*)d_in[0];   // (1,2048,1,128) -> (2048,128)
    const float* init = (const float*)d_in[1];   // (512,128)
    float* out = (float*)d_out;                  // (1,2048,512) fp32

    dim3 grid(8, 32);   // 256 blocks: exactly 1 per CU
    mmd_kernel<<<grid, THREADS, 0, stream>>>(x, init, out);
}

// Round 4
// 70.453 us; speedup vs baseline: 4.0591x; 1.5173x over previous
//
#include <hip/hip_runtime.h>

#define T_LEN 2048
#define S_LEN 512
#define D_LEN 128
#define BT 64
#define BG 80
#define THREADS 512

// out[t][s] = (1 - ||z_t - G[t+511-s]||^2 / 128)^3
//   G[g] = init[511-g] (g<512), else x[g-512]
// Norm trick: ||z-w||^2 = ||z||^2 + ||w||^2 - 2 z.w  -> inner loop is pure FMA.
//
// v5: 512-thread blocks. v3/v4 post-mortem: hipcc pins the VGPR budget at 64
// for 1024-thread workgroups regardless of __launch_bounds__ (observed: VGPR
// 64 + ~109MB scratch traffic under both (1024,4) and (1024,1)); the ~80-VGPR
// k-loop working set then spills. 512-thread kernels are known to allocate up
// to 249 VGPRs on gfx950 (HipKittens), so the same structure at 512 threads
// fits in registers.
// Structure: 256 blocks (8 g-tiles x 32 t-tiles, 64x80) = 1/CU, zero tail;
// 8 waves = 2/SIMD. K split 2 ways (sl = tid>>8, 16 float4-steps each);
// partials combined via LDS (region reused behind a barrier). Per-thread
// 4x5 tile; rotation trick ((2sl+i)&3) keeps register indices static.
// Row norms folded into staging (32-lane shfl_xor reduce). Both LDS read
// sides XOR-swizzled: z-reads 16-way broadcast, g-reads 2-way (free).

__global__ __launch_bounds__(THREADS, 2)
void mmd_kernel(const float* __restrict__ x, const float* __restrict__ init,
                float* __restrict__ out) {
    __shared__ float lds[(BT + BG) * D_LEN];   // 73,728 B; zt then gt
    __shared__ float znorm[BT];
    __shared__ float gnorm[BG];

    float* zt = lds;
    float* gt = lds + BT * D_LEN;

    const int bt = blockIdx.y;      // t-tile: 0..31
    const int j  = blockIdx.x;      // g-tile within band: 0..7
    const int t0 = bt * BT;
    const int g0 = t0 + j * BG;

    const int tid = threadIdx.x;

    // ---- stage z tile (64 rows x 32 float4), XOR swizzle on float4 columns.
    // Norm in-flight: 32 lanes per row (one row per wave-half), shfl_xor 1..16.
    #pragma unroll
    for (int k = 0; k < 4; ++k) {
        const int idx = tid + k * THREADS;
        const int row = idx >> 5;
        const int c4  = idx & 31;
        const float4 v = *(const float4*)(x + (t0 + row) * D_LEN + c4 * 4);
        *(float4*)(zt + row * D_LEN + ((c4 ^ (row & 7)) << 2)) = v;
        float s = v.x * v.x + v.y * v.y + v.z * v.z + v.w * v.w;
        s += __shfl_xor(s, 1);
        s += __shfl_xor(s, 2);
        s += __shfl_xor(s, 4);
        s += __shfl_xor(s, 8);
        s += __shfl_xor(s, 16);
        if (c4 == 0) znorm[row] = s;
    }
    // ---- stage G tile (80 rows x 32 float4 = 5 full iterations, no bounds
    //      check); clamp g (tail tiles read past the band; clamped rows only
    //      feed masked-out outputs).
    #pragma unroll
    for (int k = 0; k < 5; ++k) {
        const int idx = tid + k * THREADS;
        const int row = idx >> 5;
        const int c4  = idx & 31;
        int g = g0 + row;
        if (g > T_LEN + S_LEN - 1) g = T_LEN + S_LEN - 1;
        const float* src = (g >= S_LEN) ? (x + (g - S_LEN) * D_LEN)
                                        : (init + (S_LEN - 1 - g) * D_LEN);
        const float4 v = *(const float4*)(src + c4 * 4);
        *(float4*)(gt + row * D_LEN + ((c4 ^ (row & 7)) << 2)) = v;
        float s = v.x * v.x + v.y * v.y + v.z * v.z + v.w * v.w;
        s += __shfl_xor(s, 1);
        s += __shfl_xor(s, 2);
        s += __shfl_xor(s, 4);
        s += __shfl_xor(s, 8);
        s += __shfl_xor(s, 16);
        if (c4 == 0) gnorm[row] = s;
    }
    __syncthreads();

    const int sl = tid >> 8;       // k-slice 0..1  (wave-uniform)
    const int id = tid & 255;
    const int tx = id & 15;        // g-dir
    const int ty = id >> 4;        // t-dir

    // dot[i][jj] accumulates row-group (2*sl+i)&3 -- all register indices
    // compile-time static; sl only enters ADDRESS arithmetic.
    float dot[4][5];
    #pragma unroll
    for (int i = 0; i < 4; ++i)
        #pragma unroll
        for (int jj = 0; jj < 5; ++jj) dot[i][jj] = 0.f;

    const int zsw = ty & 7;        // z row swizzle key (row&7 == ty&7)
    const int gsw = tx & 7;        // g row swizzle key
    int zb[4], wb[5];
    #pragma unroll
    for (int i = 0; i < 4; ++i)
        zb[i] = (((2 * sl + i) & 3) * 16 + ty) * D_LEN + sl * 64;
    #pragma unroll
    for (int jj = 0; jj < 5; ++jj)
        wb[jj] = (jj * 16 + tx) * D_LEN + sl * 64;

    // kk in [0,16): logical column sl*16+kk; swizzled offset within the
    // 16-col half is (kk ^ r7) since r7 < 8 <= 16.
    #pragma unroll 4
    for (int kk = 0; kk < 16; ++kk) {
        const int zc = (kk ^ zsw) << 2;
        const int gc = (kk ^ gsw) << 2;
        float4 za[4], w[5];
        #pragma unroll
        for (int i = 0; i < 4; ++i)
            za[i] = *(const float4*)(zt + zb[i] + zc);
        #pragma unroll
        for (int jj = 0; jj < 5; ++jj)
            w[jj] = *(const float4*)(gt + wb[jj] + gc);
        #pragma unroll
        for (int i = 0; i < 4; ++i)
            #pragma unroll
            for (int jj = 0; jj < 5; ++jj)
                dot[i][jj] += za[i].x * w[jj].x + za[i].y * w[jj].y
                            + za[i].z * w[jj].z + za[i].w * w[jj].w;
    }
    __syncthreads();   // all LDS reads of zt/gt done -> region reusable

    // ---- publish partials for the partner's row-groups (dot[2], dot[3] =
    // groups (2sl+2)&3, (2sl+3)&3). Stride-1 in id -> conflict-free. 20KB.
    #pragma unroll
    for (int i = 2; i < 4; ++i) {
        const int gi = (2 * sl + i) & 3;
        #pragma unroll
        for (int jj = 0; jj < 5; ++jj)
            lds[(gi * 5 + jj) * 256 + id] = dot[i][jj];
    }
    __syncthreads();

    // ---- combine + epilogue: slice sl finalizes groups 2sl (dot[0]) and
    // 2sl+1 (dot[1]), adding the partner's published partials.
    #pragma unroll
    for (int i = 0; i < 2; ++i) {
        const int gi = 2 * sl + i;          // runtime value, address-only
        const int tr = gi * 16 + ty;
        const int t  = t0 + tr;
        const float zn = znorm[tr];
        #pragma unroll
        for (int jj = 0; jj < 5; ++jj) {
            const float tot = dot[i][jj] + lds[(gi * 5 + jj) * 256 + id];
            const int gr = jj * 16 + tx;
            const int g  = g0 + gr;
            const int so = t + (S_LEN - 1) - g;
            if (so >= 0 && so < S_LEN) {
                const float dist = zn + gnorm[gr] - 2.f * tot;
                const float p = 1.f - dist * (1.f / (float)D_LEN);
                out[t * S_LEN + so] = p * p * p;
            }
        }
    }
}

extern "C" void kernel_launch(void* const* d_in, const int* in_sizes, int n_in,
                              void* d_out, int out_size, void* d_ws, size_t ws_size,
                              hipStream_t stream) {
    (void)in_sizes; (void)n_in; (void)out_size; (void)d_ws; (void)ws_size;
    const float* x    = (const float*)d_in[0];   // (1,2048,1,128) -> (2048,128)
    const float* init = (const float*)d_in[1];   // (512,128)
    float* out = (float*)d_out;                  // (1,2048,512) fp32

    dim3 grid(8, 32);   // 256 blocks: exactly 1 per CU
    mmd_kernel<<<grid, THREADS, 0, stream>>>(x, init, out);
}

// Round 5
// 68.161 us; speedup vs baseline: 4.1956x; 1.0336x over previous
//
#include <hip/hip_runtime.h>

#define T_LEN 2048
#define S_LEN 512
#define D_LEN 128
#define BT 64
#define BG 80
#define THREADS 512

// out[t][s] = (1 - ||z_t - G[t+511-s]||^2 / 128)^3
//   G[g] = init[511-g] (g<512), else x[g-512]
// Norm trick: ||z-w||^2 = ||z||^2 + ||w||^2 - 2 z.w  -> inner loop is pure FMA.
//
// v6 = v5 with a fatter register tile to cut LDS read volume (the modeled
// bottleneck: 4x5 tile = 9 ds_read_b128 per 20 FMA4 -> 5.8us LDS pipe;
// 8x5 tile = 13 reads per 40 FMA4 -> ~4.2us).
// 512 threads = 128 tile-positions (16 px x 8 py) x 4 k-slices (sl=tid>>7,
// 8 k4-steps each). Per-thread 8x5 tile: z-rows {((2sl+i)&7)*8+py} (rotation
// trick: owned groups are always acc[0],acc[1]; all register indices static),
// g-rows {jj*16+px}.
// Bank behavior: z-reads = 4 rows/wave x 16-lane broadcast, distinct swizzle
// keys (py) -> conflict-free; g-reads 2-way (free); publish/combine stride-1.
// 256 blocks (8 x 32) = 1 block/CU, 8 waves = 2/SIMD, zero tail.

__global__ __launch_bounds__(THREADS, 2)
void mmd_kernel(const float* __restrict__ x, const float* __restrict__ init,
                float* __restrict__ out) {
    __shared__ float lds[(BT + BG) * D_LEN];   // 73,728 B; zt then gt
    __shared__ float znorm[BT];
    __shared__ float gnorm[BG];

    float* zt = lds;
    float* gt = lds + BT * D_LEN;

    const int bt = blockIdx.y;      // t-tile: 0..31
    const int j  = blockIdx.x;      // g-tile within band: 0..7
    const int t0 = bt * BT;
    const int g0 = t0 + j * BG;

    const int tid = threadIdx.x;

    // ---- stage z tile (64 rows x 32 float4), XOR swizzle on float4 columns.
    // Norm in-flight: 32 lanes per row (one row per wave-half), shfl_xor 1..16.
    #pragma unroll
    for (int k = 0; k < 4; ++k) {
        const int idx = tid + k * THREADS;
        const int row = idx >> 5;
        const int c4  = idx & 31;
        const float4 v = *(const float4*)(x + (t0 + row) * D_LEN + c4 * 4);
        *(float4*)(zt + row * D_LEN + ((c4 ^ (row & 7)) << 2)) = v;
        float s = v.x * v.x + v.y * v.y + v.z * v.z + v.w * v.w;
        s += __shfl_xor(s, 1);
        s += __shfl_xor(s, 2);
        s += __shfl_xor(s, 4);
        s += __shfl_xor(s, 8);
        s += __shfl_xor(s, 16);
        if (c4 == 0) znorm[row] = s;
    }
    // ---- stage G tile (80 rows x 32 float4 = 5 full iterations); clamp g
    //      (tail tiles read past the band; clamped rows feed masked outputs).
    #pragma unroll
    for (int k = 0; k < 5; ++k) {
        const int idx = tid + k * THREADS;
        const int row = idx >> 5;
        const int c4  = idx & 31;
        int g = g0 + row;
        if (g > T_LEN + S_LEN - 1) g = T_LEN + S_LEN - 1;
        const float* src = (g >= S_LEN) ? (x + (g - S_LEN) * D_LEN)
                                        : (init + (S_LEN - 1 - g) * D_LEN);
        const float4 v = *(const float4*)(src + c4 * 4);
        *(float4*)(gt + row * D_LEN + ((c4 ^ (row & 7)) << 2)) = v;
        float s = v.x * v.x + v.y * v.y + v.z * v.z + v.w * v.w;
        s += __shfl_xor(s, 1);
        s += __shfl_xor(s, 2);
        s += __shfl_xor(s, 4);
        s += __shfl_xor(s, 8);
        s += __shfl_xor(s, 16);
        if (c4 == 0) gnorm[row] = s;
    }
    __syncthreads();

    const int sl = tid >> 7;       // k-slice 0..3 (wave-uniform: 128 = 2 waves)
    const int id = tid & 127;
    const int px = id & 15;        // g-dir, 16 positions
    const int py = id >> 4;        // z-dir, 8 positions

    // acc[i][jj] accumulates z-group gi=(2sl+i)&7 (rows gi*8+py), g-row
    // jj*16+px. Register indices all compile-time; sl only in addresses.
    float acc[8][5];
    #pragma unroll
    for (int i = 0; i < 8; ++i)
        #pragma unroll
        for (int jj = 0; jj < 5; ++jj) acc[i][jj] = 0.f;

    const int gsw = px & 7;        // g row swizzle key
    int zb[8], wb[5];
    #pragma unroll
    for (int i = 0; i < 8; ++i)
        zb[i] = ((((2 * sl + i) & 7) * 8 + py) * D_LEN) + sl * 32;
    #pragma unroll
    for (int jj = 0; jj < 5; ++jj)
        wb[jj] = (jj * 16 + px) * D_LEN + sl * 32;

    // Slice sl covers logical c4 in [sl*8, sl*8+8). Swizzled float4-col of
    // row r: (sl*8+kk)^(r&7) = sl*8 + (kk^(r&7)) since keys < 8.
    // z-row keys are all py; g-row keys are px&7.
    #pragma unroll 2
    for (int kk = 0; kk < 8; ++kk) {
        const int zc = (kk ^ py) << 2;
        const int gc = (kk ^ gsw) << 2;
        float4 za[8], w[5];
        #pragma unroll
        for (int i = 0; i < 8; ++i)
            za[i] = *(const float4*)(zt + zb[i] + zc);
        #pragma unroll
        for (int jj = 0; jj < 5; ++jj)
            w[jj] = *(const float4*)(gt + wb[jj] + gc);
        #pragma unroll
        for (int i = 0; i < 8; ++i)
            #pragma unroll
            for (int jj = 0; jj < 5; ++jj)
                acc[i][jj] += za[i].x * w[jj].x + za[i].y * w[jj].y
                            + za[i].z * w[jj].z + za[i].w * w[jj].w;
    }
    __syncthreads();   // all LDS reads of zt/gt done -> region reusable

    // ---- publish partials for the 6 non-owned groups. For slot i>=2 the
    // owner is slice (sl+(i>>1))&3 -> source index src=(i>>1)-1 (static).
    // 8 groups x 3 srcs x 5 jj x 128 ids = 15,360 floats (61.4KB, fits).
    // Stride-1 in id -> conflict-free.
    #pragma unroll
    for (int i = 2; i < 8; ++i) {
        const int gi = (2 * sl + i) & 7;
        const int src = (i >> 1) - 1;
        #pragma unroll
        for (int jj = 0; jj < 5; ++jj)
            lds[((gi * 3 + src) * 5 + jj) * 128 + id] = acc[i][jj];
    }
    __syncthreads();

    // ---- combine + epilogue: slice sl owns groups 2sl (acc[0]), 2sl+1
    // (acc[1]); add the three published partials for each.
    #pragma unroll
    for (int i = 0; i < 2; ++i) {
        const int gi = 2 * sl + i;          // runtime value, address-only
        const int tr = gi * 8 + py;
        const int t  = t0 + tr;
        const float zn = znorm[tr];
        #pragma unroll
        for (int jj = 0; jj < 5; ++jj) {
            float tot = acc[i][jj];
            #pragma unroll
            for (int src = 0; src < 3; ++src)
                tot += lds[((gi * 3 + src) * 5 + jj) * 128 + id];
            const int gr = jj * 16 + px;
            const int g  = g0 + gr;
            const int so = t + (S_LEN - 1) - g;
            if (so >= 0 && so < S_LEN) {
                const float dist = zn + gnorm[gr] - 2.f * tot;
                const float p = 1.f - dist * (1.f / (float)D_LEN);
                out[t * S_LEN + so] = p * p * p;
            }
        }
    }
}

extern "C" void kernel_launch(void* const* d_in, const int* in_sizes, int n_in,
                              void* d_out, int out_size, void* d_ws, size_t ws_size,
                              hipStream_t stream) {
    (void)in_sizes; (void)n_in; (void)out_size; (void)d_ws; (void)ws_size;
    const float* x    = (const float*)d_in[0];   // (1,2048,1,128) -> (2048,128)
    const float* init = (const float*)d_in[1];   // (512,128)
    float* out = (float*)d_out;                  // (1,2048,512) fp32

    dim3 grid(8, 32);   // 256 blocks: exactly 1 per CU
    mmd_kernel<<<grid, THREADS, 0, stream>>>(x, init, out);
}

// Round 6
// 60.627 us; speedup vs baseline: 4.7169x; 1.1243x over previous
//
#include <hip/hip_runtime.h>

#define T_LEN 2048
#define S_LEN 512
#define D_LEN 128
#define BT 64
#define BG 80
#define THREADS 512

// out[t][s] = (1 - ||z_t - G[t+511-s]||^2 / 128)^3
//   G[g] = init[511-g] (g<512), else x[g-512]
// Norm trick: ||z-w||^2 = ||z||^2 + ||w||^2 - 2 z.w.
//
// v7: the dot matrix (64x80 per block, K=128) moves to MFMA via split-bf16:
//   z = zh + zl (bf16 RNE + bf16 residual); dot = zh.wh + zh.wl + zl.wh,
//   fp32 accumulation. Dropped zl.wl term ~3e-4 on dist -> ~1e-5 on output.
// Kills the v6 VALU k-loop (2560 cyc/wave -> ~110) and the k-split
// publish/combine (each wave owns whole-K output tiles).
// LDS: hi/lo planes Z[64][128], G[80][128] bf16 as 16B chunks (8 elems),
// chunk slot = c ^ (row&15) swizzle -> every wave access lands 8 addresses
// per bank-quad = structural minimum (conflict-free).
// Frag loads: A lane l: row=l&15 (+16*R), k-chunk = q*4+(l>>4); B identical.
// Internal MFMA k-ordering cancels (same (group,elem)->k map on both sides).
// C/D layout (HW-measured m89): col=lane&15, row=(lane>>4)*4+reg.
// Waves: wid>>1 = row-tile R (0..3), wid&1 selects col-tiles {0,1,2} or {3,4}.
// 256 blocks (8 x 32) = 1 block/CU, 512 thr; norms folded into staging.

typedef __attribute__((ext_vector_type(8))) short short8;
typedef __attribute__((ext_vector_type(4))) float f32x4;

__device__ __forceinline__ unsigned int bf16_rne(float f) {
    unsigned int u = __float_as_uint(f);
    u += 0x7FFFu + ((u >> 16) & 1u);
    return u >> 16;
}

__global__ __launch_bounds__(THREADS, 2)
void mmd_kernel(const float* __restrict__ x, const float* __restrict__ init,
                float* __restrict__ out) {
    __shared__ uint4 zh4[BT * 16];     // 16 KB  Z hi plane, 16B chunks
    __shared__ uint4 zl4[BT * 16];     // 16 KB  Z lo plane
    __shared__ uint4 gh4[BG * 16];     // 20 KB  G hi plane
    __shared__ uint4 gl4[BG * 16];     // 20 KB  G lo plane
    __shared__ float znorm[BT];
    __shared__ float gnorm[BG];

    const int t0 = blockIdx.y * BT;
    const int g0 = t0 + blockIdx.x * BG;
    const int tid = threadIdx.x;

    // ---- stage Z: 64 rows x 16 chunks (8 fp32 -> 8 bf16 hi + 8 bf16 lo).
    // Norm in fp32 from the original values; 16-lane shfl reduce per row.
    #pragma unroll
    for (int k = 0; k < 2; ++k) {
        const int idx = tid + k * THREADS;
        const int row = idx >> 4;
        const int c   = idx & 15;
        const float* p = x + (t0 + row) * D_LEN + c * 8;
        const float4 va = *(const float4*)p;
        const float4 vb = *(const float4*)(p + 4);
        const float f[8] = {va.x, va.y, va.z, va.w, vb.x, vb.y, vb.z, vb.w};
        unsigned int h[8], l[8];
        float nrm = 0.f;
        #pragma unroll
        for (int e = 0; e < 8; ++e) {
            nrm += f[e] * f[e];
            h[e] = bf16_rne(f[e]);
            const float fh = __uint_as_float(h[e] << 16);
            l[e] = bf16_rne(f[e] - fh);
        }
        uint4 H, L;
        H.x = h[0] | (h[1] << 16); H.y = h[2] | (h[3] << 16);
        H.z = h[4] | (h[5] << 16); H.w = h[6] | (h[7] << 16);
        L.x = l[0] | (l[1] << 16); L.y = l[2] | (l[3] << 16);
        L.z = l[4] | (l[5] << 16); L.w = l[6] | (l[7] << 16);
        const int slot = c ^ (row & 15);
        zh4[row * 16 + slot] = H;
        zl4[row * 16 + slot] = L;
        nrm += __shfl_xor(nrm, 1);
        nrm += __shfl_xor(nrm, 2);
        nrm += __shfl_xor(nrm, 4);
        nrm += __shfl_xor(nrm, 8);
        if (c == 0) znorm[row] = nrm;
    }
    // ---- stage G: 80 rows x 16 chunks; clamp g (tail tiles read past the
    // band; clamped rows only feed masked-out outputs).
    #pragma unroll
    for (int k = 0; k < 3; ++k) {
        const int idx = tid + k * THREADS;
        if (idx < BG * 16) {
            const int row = idx >> 4;
            const int c   = idx & 15;
            int g = g0 + row;
            if (g > T_LEN + S_LEN - 1) g = T_LEN + S_LEN - 1;
            const float* src = (g >= S_LEN) ? (x + (g - S_LEN) * D_LEN)
                                            : (init + (S_LEN - 1 - g) * D_LEN);
            const float4 va = *(const float4*)(src + c * 8);
            const float4 vb = *(const float4*)(src + c * 8 + 4);
            const float f[8] = {va.x, va.y, va.z, va.w, vb.x, vb.y, vb.z, vb.w};
            unsigned int h[8], l[8];
            float nrm = 0.f;
            #pragma unroll
            for (int e = 0; e < 8; ++e) {
                nrm += f[e] * f[e];
                h[e] = bf16_rne(f[e]);
                const float fh = __uint_as_float(h[e] << 16);
                l[e] = bf16_rne(f[e] - fh);
            }
            uint4 H, L;
            H.x = h[0] | (h[1] << 16); H.y = h[2] | (h[3] << 16);
            H.z = h[4] | (h[5] << 16); H.w = h[6] | (h[7] << 16);
            L.x = l[0] | (l[1] << 16); L.y = l[2] | (l[3] << 16);
            L.z = l[4] | (l[5] << 16); L.w = l[6] | (l[7] << 16);
            const int slot = c ^ (row & 15);
            gh4[row * 16 + slot] = H;
            gl4[row * 16 + slot] = L;
            nrm += __shfl_xor(nrm, 1);
            nrm += __shfl_xor(nrm, 2);
            nrm += __shfl_xor(nrm, 4);
            nrm += __shfl_xor(nrm, 8);
            if (c == 0) gnorm[row] = nrm;
        }
    }
    __syncthreads();

    // ---- MFMA phase
    const int lane = tid & 63;
    const int wid  = tid >> 6;
    const int r16  = lane & 15;
    const int g4   = lane >> 4;
    const int R    = wid >> 1;           // row-tile 0..3
    const int half = wid & 1;
    const int cb   = half ? 3 : 0;       // first col-tile
    const int nt   = half ? 2 : 3;       // #col-tiles this wave

    f32x4 acc[3];
    #pragma unroll
    for (int ti = 0; ti < 3; ++ti) acc[ti] = (f32x4){0.f, 0.f, 0.f, 0.f};

    const int arow = R * 16 + r16;       // z LDS row (low 4 bits == r16)

    #pragma unroll
    for (int q = 0; q < 4; ++q) {
        const int slot = (q * 4 + g4) ^ r16;
        const short8 Ah = *(const short8*)(zh4 + arow * 16 + slot);
        const short8 Al = *(const short8*)(zl4 + arow * 16 + slot);
        #pragma unroll
        for (int ti = 0; ti < 3; ++ti) {
            if (ti < nt) {
                const int gi = ((cb + ti) * 16 + r16) * 16 + slot;
                const short8 Bh = *(const short8*)(gh4 + gi);
                const short8 Bl = *(const short8*)(gl4 + gi);
                acc[ti] = __builtin_amdgcn_mfma_f32_16x16x32_bf16(Ah, Bh, acc[ti], 0, 0, 0);
                acc[ti] = __builtin_amdgcn_mfma_f32_16x16x32_bf16(Ah, Bl, acc[ti], 0, 0, 0);
                acc[ti] = __builtin_amdgcn_mfma_f32_16x16x32_bf16(Al, Bh, acc[ti], 0, 0, 0);
            }
        }
    }

    // ---- epilogue: C layout col=lane&15, row=(lane>>4)*4+reg (m89).
    #pragma unroll
    for (int ti = 0; ti < 3; ++ti) {
        if (ti < nt) {
            const int gr = (cb + ti) * 16 + r16;
            const int g  = g0 + gr;
            const float gn = gnorm[gr];
            #pragma unroll
            for (int reg = 0; reg < 4; ++reg) {
                const int row = R * 16 + g4 * 4 + reg;
                const int t   = t0 + row;
                const int s   = t + (S_LEN - 1) - g;
                if (s >= 0 && s < S_LEN) {
                    const float dist = znorm[row] + gn - 2.f * acc[ti][reg];
                    const float p = 1.f - dist * (1.f / (float)D_LEN);
                    out[t * S_LEN + s] = p * p * p;
                }
            }
        }
    }
}

extern "C" void kernel_launch(void* const* d_in, const int* in_sizes, int n_in,
                              void* d_out, int out_size, void* d_ws, size_t ws_size,
                              hipStream_t stream) {
    (void)in_sizes; (void)n_in; (void)out_size; (void)d_ws; (void)ws_size;
    const float* x    = (const float*)d_in[0];   // (1,2048,1,128) -> (2048,128)
    const float* init = (const float*)d_in[1];   // (512,128)
    float* out = (float*)d_out;                  // (1,2048,512) fp32

    dim3 grid(8, 32);   // 256 blocks: exactly 1 per CU
    mmd_kernel<<<grid, THREADS, 0, stream>>>(x, init, out);
}

// Round 8
// 59.779 us; speedup vs baseline: 4.7838x; 1.0142x over previous
//
#include <hip/hip_runtime.h>

#define T_LEN 2048
#define S_LEN 512
#define D_LEN 128
#define BT 64
#define BG 80
#define THREADS 512

// out[t][s] = (1 - ||z_t - G[t+511-s]||^2 / 128)^3
//   G[g] = init[511-g] (g<512), else x[g-512]
// Norm trick: ||z-w||^2 = ||z||^2 + ||w||^2 - 2 z.w.
//
// v8 = v7 with the dot on a SINGLE fp16 plane (was split-bf16, 3 MFMAs).
// Inputs are N(0,1) -> fp16's 11-bit significand gives dist err ~0.01,
// output err ~1.5e-3 (<< the 0.03 absmax already passing). Norms stay
// exact fp32 from staging, so the diagonal (dist~0) region is anchored.
// Wins vs v7: staging conversion 72 VALU/chunk -> ~12 (v_cvt_pkrtz x4 +
// 8 norm FMAs), one LDS plane per operand (36KB total), MFMA-phase
// ds_reads 32 -> 16 per wave, MFMAs 36 -> 12 per wave.
// Structure unchanged (verified in v7): 256 blocks (8x32) = 1/CU, 512 thr;
// chunk-slot swizzle slot = c ^ (row&15); A lane l: row=l&15 (+16R),
// chunk q*4+(l>>4); internal MFMA k-order cancels (same map both sides);
// C/D layout col=lane&15, row=(lane>>4)*4+reg (m89, dtype-independent).
// (v8 first attempt failed to compile: cvt_pkrtz returns __fp16x2, not
// _Float16x2 — bit-cast from the builtin's own return type.)

typedef _Float16 half8 __attribute__((ext_vector_type(8)));
typedef __attribute__((ext_vector_type(4))) float f32x4;

__device__ __forceinline__ unsigned int pk2(float a, float b) {
    return __builtin_bit_cast(unsigned int, __builtin_amdgcn_cvt_pkrtz(a, b));
}

__global__ __launch_bounds__(THREADS, 2)
void mmd_kernel(const float* __restrict__ x, const float* __restrict__ init,
                float* __restrict__ out) {
    __shared__ uint4 zf[BT * 16];      // 16 KB  Z fp16 plane, 16B chunks
    __shared__ uint4 gf[BG * 16];      // 20 KB  G fp16 plane
    __shared__ float znorm[BT];
    __shared__ float gnorm[BG];

    const int t0 = blockIdx.y * BT;
    const int g0 = t0 + blockIdx.x * BG;
    const int tid = threadIdx.x;

    // ---- stage Z: 64 rows x 16 chunks (8 fp32 -> 8 fp16), norm in fp32.
    // 16 lanes per row; shfl_xor 1..8 reduces the norm within the row group.
    #pragma unroll
    for (int k = 0; k < 2; ++k) {
        const int idx = tid + k * THREADS;
        const int row = idx >> 4;
        const int c   = idx & 15;
        const float* p = x + (t0 + row) * D_LEN + c * 8;
        const float4 va = *(const float4*)p;
        const float4 vb = *(const float4*)(p + 4);
        float nrm = va.x * va.x + va.y * va.y + va.z * va.z + va.w * va.w
                  + vb.x * vb.x + vb.y * vb.y + vb.z * vb.z + vb.w * vb.w;
        uint4 H;
        H.x = pk2(va.x, va.y); H.y = pk2(va.z, va.w);
        H.z = pk2(vb.x, vb.y); H.w = pk2(vb.z, vb.w);
        zf[row * 16 + (c ^ (row & 15))] = H;
        nrm += __shfl_xor(nrm, 1);
        nrm += __shfl_xor(nrm, 2);
        nrm += __shfl_xor(nrm, 4);
        nrm += __shfl_xor(nrm, 8);
        if (c == 0) znorm[row] = nrm;
    }
    // ---- stage G: 80 rows x 16 chunks; clamp g (tail tiles read past the
    // band; clamped rows only feed masked-out outputs).
    #pragma unroll
    for (int k = 0; k < 3; ++k) {
        const int idx = tid + k * THREADS;
        if (idx < BG * 16) {
            const int row = idx >> 4;
            const int c   = idx & 15;
            int g = g0 + row;
            if (g > T_LEN + S_LEN - 1) g = T_LEN + S_LEN - 1;
            const float* src = (g >= S_LEN) ? (x + (g - S_LEN) * D_LEN)
                                            : (init + (S_LEN - 1 - g) * D_LEN);
            const float4 va = *(const float4*)(src + c * 8);
            const float4 vb = *(const float4*)(src + c * 8 + 4);
            float nrm = va.x * va.x + va.y * va.y + va.z * va.z + va.w * va.w
                      + vb.x * vb.x + vb.y * vb.y + vb.z * vb.z + vb.w * vb.w;
            uint4 H;
            H.x = pk2(va.x, va.y); H.y = pk2(va.z, va.w);
            H.z = pk2(vb.x, vb.y); H.w = pk2(vb.z, vb.w);
            gf[row * 16 + (c ^ (row & 15))] = H;
            nrm += __shfl_xor(nrm, 1);
            nrm += __shfl_xor(nrm, 2);
            nrm += __shfl_xor(nrm, 4);
            nrm += __shfl_xor(nrm, 8);
            if (c == 0) gnorm[row] = nrm;
        }
    }
    __syncthreads();

    // ---- MFMA phase: wid>>1 = row-tile R (0..3); wid&1 picks col-tiles
    // {0,1,2} or {3,4} of the 5 16-wide G tiles.
    const int lane = tid & 63;
    const int wid  = tid >> 6;
    const int r16  = lane & 15;
    const int g4   = lane >> 4;
    const int R    = wid >> 1;
    const int half = wid & 1;
    const int cb   = half ? 3 : 0;
    const int nt   = half ? 2 : 3;

    f32x4 acc[3];
    #pragma unroll
    for (int ti = 0; ti < 3; ++ti) acc[ti] = (f32x4){0.f, 0.f, 0.f, 0.f};

    const int arow = R * 16 + r16;

    #pragma unroll
    for (int q = 0; q < 4; ++q) {
        const int slot = (q * 4 + g4) ^ r16;
        const half8 A = *(const half8*)(zf + arow * 16 + slot);
        #pragma unroll
        for (int ti = 0; ti < 3; ++ti) {
            if (ti < nt) {
                const half8 B = *(const half8*)(gf + ((cb + ti) * 16 + r16) * 16 + slot);
                acc[ti] = __builtin_amdgcn_mfma_f32_16x16x32_f16(A, B, acc[ti], 0, 0, 0);
            }
        }
    }

    // ---- epilogue: C layout col=lane&15, row=(lane>>4)*4+reg (m89).
    #pragma unroll
    for (int ti = 0; ti < 3; ++ti) {
        if (ti < nt) {
            const int gr = (cb + ti) * 16 + r16;
            const int g  = g0 + gr;
            const float gn = gnorm[gr];
            #pragma unroll
            for (int reg = 0; reg < 4; ++reg) {
                const int row = R * 16 + g4 * 4 + reg;
                const int t   = t0 + row;
                const int s   = t + (S_LEN - 1) - g;
                if (s >= 0 && s < S_LEN) {
                    const float dist = znorm[row] + gn - 2.f * acc[ti][reg];
                    const float p = 1.f - dist * (1.f / (float)D_LEN);
                    out[t * S_LEN + s] = p * p * p;
                }
            }
        }
    }
}

extern "C" void kernel_launch(void* const* d_in, const int* in_sizes, int n_in,
                              void* d_out, int out_size, void* d_ws, size_t ws_size,
                              hipStream_t stream) {
    (void)in_sizes; (void)n_in; (void)out_size; (void)d_ws; (void)ws_size;
    const float* x    = (const float*)d_in[0];   // (1,2048,1,128) -> (2048,128)
    const float* init = (const float*)d_in[1];   // (512,128)
    float* out = (float*)d_out;                  // (1,2048,512) fp32

    dim3 grid(8, 32);   // 256 blocks: exactly 1 per CU
    mmd_kernel<<<grid, THREADS, 0, stream>>>(x, init, out);
}